// Round 1
// baseline (152.871 us; speedup 1.0000x reference)
//
#include <hip/hip_runtime.h>
#include <hip/hip_bf16.h>

#define NN 1500
#define GIN 32
#define GOUT 8
#define HID 128
#define CAP 192           // max nnz/row kept; mean ~60, sigma ~7.6 -> 17 sigma headroom

typedef _Float16 h2 __attribute__((ext_vector_type(2)));

__device__ __forceinline__ h2 u2h(unsigned int x) { return __builtin_bit_cast(h2, x); }
__device__ __forceinline__ unsigned int h2u(h2 x) { return __builtin_bit_cast(unsigned int, x); }

// ---------------------------------------------------------------------------
// Fused: compact combined adjacency row (geo+sem > 0) into LDS, write CSR for
// layers 2-3, and compute GAT layer 1 attention for this row in one kernel.
// One block (256 thr) per row.
// R11: attention edge work split across lane PAIRS (each half covers 16 of the
// 32 input channels, combined via shfl_xor(.,1)) -> engages up to 120 lanes
// instead of ~60 and halves the per-lane FMA tail + gather bytes.
// ---------------------------------------------------------------------------
__global__ void gat_first(const float* __restrict__ geo,
                          const float* __restrict__ sem,
                          const float* __restrict__ feat,   // NN x 32
                          const float* __restrict__ W0,     // 32 x 8
                          const float* __restrict__ a0,     // 16
                          int* __restrict__ csr_idx,
                          float* __restrict__ csr_val,
                          int* __restrict__ csr_cnt,
                          float* __restrict__ enc_out) {
    const int i = blockIdx.x;
    const int t = threadIdx.x;  // 256
    __shared__ int cnt;
    __shared__ int sidx[CAP];
    __shared__ float sval[CAP];
    __shared__ float hi_s[GOUT];
    __shared__ float wsum[4][GOUT + 1];
    if (t == 0) cnt = 0;
    __syncthreads();

    const float* grow = geo + (size_t)i * NN;
    const float* srow = sem + (size_t)i * NN;
    for (int q = t; q < NN / 4; q += 256) {
        float4 g = *(const float4*)(grow + 4 * q);
        float4 s = *(const float4*)(srow + 4 * q);
        float a[4] = {g.x + s.x, g.y + s.y, g.z + s.z, g.w + s.w};
        #pragma unroll
        for (int c = 0; c < 4; ++c) {
            if (a[c] > 0.f) {
                int p = atomicAdd(&cnt, 1);
                if (p < CAP) { sidx[p] = 4 * q + c; sval[p] = a[c]; }
            }
        }
    }
    // h_i (only needed for f_src): threads 0..7
    if (t < GOUT) {
        float hv = 0.f;
        #pragma unroll 4
        for (int c = 0; c < GIN; ++c)
            hv = fmaf(feat[(size_t)i * GIN + c], W0[c * GOUT + t], hv);
        hi_s[t] = hv;
    }
    __syncthreads();

    const int c2 = cnt < CAP ? cnt : CAP;
    if (t == 0) csr_cnt[i] = c2;
    for (int p = t; p < c2; p += 256) {
        csr_idx[(size_t)i * CAP + p] = sidx[p];
        csr_val[(size_t)i * CAP + p] = sval[p];
    }
    float fsrc = 0.f;
    #pragma unroll
    for (int k = 0; k < GOUT; ++k) fsrc = fmaf(hi_s[k], a0[k], fsrc);

    // attention: one edge per lane PAIR (128 pairs/pass; CAP=192 -> <=2 passes)
    float den = 0.f;
    float num[GOUT] = {};
    const int half = t & 1;
    for (int e0 = 0; e0 < c2; e0 += 128) {
        int e = e0 + (t >> 1);
        if (e < c2) {
            int j = sidx[e];
            float aw = sval[e];
            const float* fj = feat + (size_t)j * GIN + 16 * half;
            const float* w0 = W0 + (size_t)(16 * half) * GOUT;
            float hj[GOUT] = {};
            #pragma unroll
            for (int c4 = 0; c4 < 4; ++c4) {
                float4 e4 = *(const float4*)(fj + 4 * c4);
                const float* ep = (const float*)&e4;
                #pragma unroll
                for (int c = 0; c < 4; ++c)
                    #pragma unroll
                    for (int k = 0; k < GOUT; ++k)
                        hj[k] = fmaf(ep[c], w0[(4 * c4 + c) * GOUT + k], hj[k]);
            }
            // combine the two halves: partner lane (t^1) has the same e
            #pragma unroll
            for (int k = 0; k < GOUT; ++k) hj[k] += __shfl_xor(hj[k], 1, 64);
            if (half == 0) {
                float fd = 0.f;
                #pragma unroll
                for (int k = 0; k < GOUT; ++k) fd = fmaf(hj[k], a0[GOUT + k], fd);
                float ev = fsrc + fd;
                ev = (ev > 0.f) ? ev : 0.2f * ev;
                ev *= aw;
                float p = __expf(ev);
                den += p;
                #pragma unroll
                for (int k = 0; k < GOUT; ++k) num[k] = fmaf(p, hj[k], num[k]);
            }
        }
    }
    #pragma unroll
    for (int off = 32; off > 0; off >>= 1) {
        den += __shfl_xor(den, off, 64);
        #pragma unroll
        for (int k = 0; k < GOUT; ++k) num[k] += __shfl_xor(num[k], off, 64);
    }
    if ((t & 63) == 0) {
        wsum[t >> 6][0] = den;
        #pragma unroll
        for (int k = 0; k < GOUT; ++k) wsum[t >> 6][1 + k] = num[k];
    }
    __syncthreads();
    if (t < GOUT) {
        float L = wsum[0][0] + wsum[1][0] + wsum[2][0] + wsum[3][0];
        float v = (wsum[0][1 + t] + wsum[1][1 + t] + wsum[2][1 + t] + wsum[3][1 + t]) / L;
        enc_out[(size_t)i * GOUT + t] = (v > 0.f) ? v : (__expf(v) - 1.f);
    }
}

// ---------------------------------------------------------------------------
// GAT layers 2,3: one WAVE per row i, CSR-driven. When UV=true (layer 3),
// the wave also computes U[i,:], V[i,:] (stored as f16 for the packed-math
// MLP), A[i]=sum_k U*f2, B[i]=sum_k V*f2 (fp32 rank-1 split), and row 0's
// wave writes c = sum_k w16*f2 plus f16 copies of w16 and fc2w.
// ---------------------------------------------------------------------------
template<int IN, bool UV>
__global__ void gat_layer(const float* __restrict__ enc,
                          const float* __restrict__ W,     // IN x 8
                          const float* __restrict__ avec,  // 16
                          const int* __restrict__ csr_idx,
                          const float* __restrict__ csr_val,
                          const int* __restrict__ csr_cnt,
                          float* __restrict__ enc_out,
                          const float* __restrict__ fc1w,  // 17 x 128
                          const float* __restrict__ fc1b,  // 128
                          const float* __restrict__ fc2w,  // 128
                          _Float16* __restrict__ Uh, _Float16* __restrict__ Vh,
                          _Float16* __restrict__ wh, _Float16* __restrict__ fh,
                          float* __restrict__ Arow, float* __restrict__ Bcol,
                          float* __restrict__ cptr) {
    const int tid = threadIdx.x;            // 256 = 4 waves, 1 wave per row
    const int lane = tid & 63;
    const int i = blockIdx.x * 4 + (tid >> 6);   // 375*4 == 1500 exact

    float hv = 0.f;
    if (lane < GOUT) {
        #pragma unroll 4
        for (int c = 0; c < IN; ++c)
            hv = fmaf(enc[(size_t)i * IN + c], W[c * GOUT + lane], hv);
    }
    float hi[GOUT];
    #pragma unroll
    for (int c = 0; c < GOUT; ++c) hi[c] = __shfl(hv, c, 64);
    float fsrc = 0.f;
    #pragma unroll
    for (int c = 0; c < GOUT; ++c) fsrc = fmaf(hi[c], avec[c], fsrc);

    const int cnt = csr_cnt[i];
    float den = 0.f;
    float num[GOUT] = {};
    for (int e = lane; e < cnt; e += 64) {
        int j = csr_idx[(size_t)i * CAP + e];
        float a = csr_val[(size_t)i * CAP + e];
        float hj[GOUT] = {};
        #pragma unroll
        for (int c4 = 0; c4 < IN / 4; ++c4) {
            float4 e4 = *(const float4*)(enc + (size_t)j * IN + 4 * c4);
            const float* ep = (const float*)&e4;
            #pragma unroll
            for (int c = 0; c < 4; ++c)
                #pragma unroll
                for (int k = 0; k < GOUT; ++k)
                    hj[k] = fmaf(ep[c], W[(4 * c4 + c) * GOUT + k], hj[k]);
        }
        float fd = 0.f;
        #pragma unroll
        for (int k = 0; k < GOUT; ++k) fd = fmaf(hj[k], avec[GOUT + k], fd);
        float ev = fsrc + fd;
        ev = (ev > 0.f) ? ev : 0.2f * ev;
        ev *= a;
        float p = __expf(ev);
        den += p;
        #pragma unroll
        for (int k = 0; k < GOUT; ++k) num[k] = fmaf(p, hj[k], num[k]);
    }
    #pragma unroll
    for (int off = 32; off > 0; off >>= 1) {
        den += __shfl_xor(den, off, 64);
        #pragma unroll
        for (int k = 0; k < GOUT; ++k) num[k] += __shfl_xor(num[k], off, 64);
    }
    // elu output for this row (valid at lanes 0..7)
    float vout = 0.f;
    if (lane < GOUT) {
        float v = num[lane] / den;
        vout = (v > 0.f) ? v : (__expf(v) - 1.f);
        enc_out[(size_t)i * GOUT + lane] = vout;
    }

    if constexpr (UV) {
        float er[GOUT];
        #pragma unroll
        for (int c = 0; c < GOUT; ++c) er[c] = __shfl(vout, c, 64);
        const int kl = lane, kh = lane + 64;
        float u_lo = fc1b[kl], u_hi = fc1b[kh];
        float v_lo = 0.f, v_hi = 0.f;
        #pragma unroll
        for (int c = 0; c < GOUT; ++c) {
            u_lo = fmaf(er[c], fc1w[c * HID + kl], u_lo);
            u_hi = fmaf(er[c], fc1w[c * HID + kh], u_hi);
            v_lo = fmaf(er[c], fc1w[(GOUT + c) * HID + kl], v_lo);
            v_hi = fmaf(er[c], fc1w[(GOUT + c) * HID + kh], v_hi);
        }
        Uh[(size_t)i * HID + kl] = (_Float16)u_lo;
        Uh[(size_t)i * HID + kh] = (_Float16)u_hi;
        Vh[(size_t)i * HID + kl] = (_Float16)v_lo;
        Vh[(size_t)i * HID + kh] = (_Float16)v_hi;
        const float f_lo = fc2w[kl], f_hi = fc2w[kh];
        float ap = u_lo * f_lo + u_hi * f_hi;
        float bp = v_lo * f_lo + v_hi * f_hi;
        #pragma unroll
        for (int off = 32; off > 0; off >>= 1) {
            ap += __shfl_xor(ap, off, 64);
            bp += __shfl_xor(bp, off, 64);
        }
        if (lane == 0) { Arow[i] = ap; Bcol[i] = bp; }
        if (i == 0) {
            const float* w16g = fc1w + 2 * GOUT * HID;
            wh[kl] = (_Float16)w16g[kl];
            wh[kh] = (_Float16)w16g[kh];
            fh[kl] = (_Float16)f_lo;
            fh[kh] = (_Float16)f_hi;
            float cp = w16g[kl] * f_lo + w16g[kh] * f_hi;
            #pragma unroll
            for (int off = 32; off > 0; off >>= 1) cp += __shfl_xor(cp, off, 64);
            if (lane == 0) cptr[0] = cp;
        }
    }
}

// ---------------------------------------------------------------------------
// Pair-MLP, LDS-free lane=j, packed f16 (R10), q-outer/r-inner scalar-load
// batching (R8-R10). R11: per-lane V-row loads software-pipelined one c4
// chunk ahead (vn prefetch) so the q=0 burst of chunk c4+1 never waits on
// vmcnt; c4==3 prefetch wraps to chunk 0 (redundant 64B, dead after loop).
//   per 2 k: v_pk_add_f16, v_pk_fma_f16, v_and_b32 (|.|), v_dot2_f32_f16
//   out = fc2b + 0.5*(A_i + B_j + d*c) + 0.5*sum_k |U+V+d*w16|*f2  (relu->abs)
// Grid 6 x 250 = 1500 blocks = ~5.9 waves/SIMD.
// ---------------------------------------------------------------------------
#define IB 6

__global__ __launch_bounds__(256, 6) void mlp_kernel(
        const _Float16* __restrict__ Uh, const _Float16* __restrict__ Vh,
        const _Float16* __restrict__ wh, const _Float16* __restrict__ fh,
        const float* __restrict__ Arow, const float* __restrict__ Bcol,
        const float* __restrict__ cptr,
        const float* __restrict__ dist,
        const float* __restrict__ fc2b,   // 1
        float* __restrict__ out) {
    const int tid = threadIdx.x;
    const int j = blockIdx.x * 256 + tid;        // 6*256 = 1536 covers 1500
    const int jc = j < NN ? j : NN - 1;
    const int i0 = blockIdx.y * IB;              // 250*6 = 1500 exact

    // distance strip (fp32 for epilogue + f16-pair splat for the inner fma)
    float d[IB], acc[IB];
    h2 d2[IB];
    #pragma unroll
    for (int r = 0; r < IB; ++r) {
        d[r] = dist[(size_t)(i0 + r) * NN + jc];
        acc[r] = 0.f;
        _Float16 dh = (_Float16)d[r];
        d2[r] = h2{dh, dh};
    }

    const uint4* Vrow = (const uint4*)(Vh + (size_t)jc * HID);  // 16 x uint4
    const uint4* Wt = (const uint4*)wh;
    const uint4* Ft = (const uint4*)fh;

    // prime the V pipeline: chunk 0
    uint4 vv[4];
    #pragma unroll
    for (int q = 0; q < 4; ++q) vv[q] = Vrow[q];

    for (int c4 = 0; c4 < 4; ++c4) {    // 4 chunks of 32 k (8 f16 per uint4)
        // prefetch next chunk's V (wraps to 0 at c4==3; result discarded)
        const int c4n = (c4 + 1) & 3;
        uint4 vn[4], ww[4], ff[4];
        #pragma unroll
        for (int q = 0; q < 4; ++q) {
            vn[q] = Vrow[c4n * 4 + q];  // per-lane VMEM, in flight across burst
            ww[q] = Wt[c4 * 4 + q];     // wave-uniform -> s_load
            ff[q] = Ft[c4 * 4 + q];
        }
        #pragma unroll
        for (int q = 0; q < 4; ++q) {
            // batch all IB row-loads for this q (wave-uniform -> s_load x IB)
            uint4 uu[IB];
            #pragma unroll
            for (int r = 0; r < IB; ++r)
                uu[r] = *((const uint4*)(Uh + (size_t)(i0 + r) * HID) + c4 * 4 + q);
            const unsigned int ve[4] = {vv[q].x, vv[q].y, vv[q].z, vv[q].w};
            const unsigned int we[4] = {ww[q].x, ww[q].y, ww[q].z, ww[q].w};
            const unsigned int fe[4] = {ff[q].x, ff[q].y, ff[q].z, ff[q].w};
            #pragma unroll
            for (int r = 0; r < IB; ++r) {
                const unsigned int ue[4] = {uu[r].x, uu[r].y, uu[r].z, uu[r].w};
                #pragma unroll
                for (int e = 0; e < 4; ++e) {
                    h2 t = u2h(ue[e]) + u2h(ve[e]);                       // v_pk_add_f16
                    t = __builtin_elementwise_fma(d2[r], u2h(we[e]), t);  // v_pk_fma_f16
                    t = u2h(h2u(t) & 0x7fff7fffu);                        // |.| both halves
                    acc[r] = __builtin_amdgcn_fdot2(t, u2h(fe[e]), acc[r], false);
                }
            }
        }
        #pragma unroll
        for (int q = 0; q < 4; ++q) vv[q] = vn[q];
    }

    // epilogue: fp32 rank-1 linear half + bias, coalesced stores
    if (j < NN) {
        const float c = cptr[0];
        const float b2 = fc2b[0];
        const float Bj = Bcol[jc];
        #pragma unroll
        for (int r = 0; r < IB; ++r) {
            float lin = Arow[i0 + r] + Bj + d[r] * c;
            out[(size_t)(i0 + r) * NN + j] = fmaf(0.5f, lin + acc[r], b2);
        }
    }
}

// ---------------------------------------------------------------------------
extern "C" void kernel_launch(void* const* d_in, const int* in_sizes, int n_in,
                              void* d_out, int out_size, void* d_ws, size_t ws_size,
                              hipStream_t stream) {
    const float* geo  = (const float*)d_in[0];
    const float* sem  = (const float*)d_in[1];
    const float* feat = (const float*)d_in[2];
    // d_in[3] = region_pairs: full meshgrid -> row-major (i,j); unused
    const float* dist = (const float*)d_in[4];
    const float* W0   = (const float*)d_in[5];
    const float* W1   = (const float*)d_in[6];
    const float* W2   = (const float*)d_in[7];
    const float* a0   = (const float*)d_in[8];
    const float* a1   = (const float*)d_in[9];
    const float* a2   = (const float*)d_in[10];
    const float* fc1w = (const float*)d_in[11];
    const float* fc1b = (const float*)d_in[12];
    const float* fc2w = (const float*)d_in[13];
    const float* fc2b = (const float*)d_in[14];
    float* out = (float*)d_out;

    // workspace layout (~3.5 MB); all chunk sizes keep 16B alignment
    char* ws = (char*)d_ws;
    int*      csr_idx = (int*)ws;                     ws += sizeof(int) * NN * CAP;
    float*    csr_val = (float*)ws;                   ws += sizeof(float) * NN * CAP;
    int*      csr_cnt = (int*)ws;                     ws += sizeof(int) * NN;
    float*    encA    = (float*)ws;                   ws += sizeof(float) * NN * GOUT;
    float*    encB    = (float*)ws;                   ws += sizeof(float) * NN * GOUT;
    _Float16* Uh      = (_Float16*)ws;                ws += sizeof(_Float16) * NN * HID;
    _Float16* Vh      = (_Float16*)ws;                ws += sizeof(_Float16) * NN * HID;
    _Float16* wh      = (_Float16*)ws;                ws += sizeof(_Float16) * HID;
    _Float16* fh      = (_Float16*)ws;                ws += sizeof(_Float16) * HID;
    float*    Ar      = (float*)ws;                   ws += sizeof(float) * NN;
    float*    Bc      = (float*)ws;                   ws += sizeof(float) * NN;
    float*    cptr    = (float*)ws;

    gat_first<<<NN, 256, 0, stream>>>(geo, sem, feat, W0, a0,
                                      csr_idx, csr_val, csr_cnt, encA);
    gat_layer<GOUT, false><<<NN / 4, 256, 0, stream>>>(
        encA, W1, a1, csr_idx, csr_val, csr_cnt, encB,
        nullptr, nullptr, nullptr,
        nullptr, nullptr, nullptr, nullptr, nullptr, nullptr, nullptr);
    gat_layer<GOUT, true><<<NN / 4, 256, 0, stream>>>(
        encB, W2, a2, csr_idx, csr_val, csr_cnt, encA,
        fc1w, fc1b, fc2w, Uh, Vh, wh, fh, Ar, Bc, cptr);

    dim3 mg((NN + 255) / 256, (NN + IB - 1) / IB);   // 6 x 250
    mlp_kernel<<<mg, 256, 0, stream>>>(Uh, Vh, wh, fh, Ar, Bc, cptr,
                                       dist, fc2b, out);
}

// Round 2
// 147.988 us; speedup vs baseline: 1.0330x; 1.0330x over previous
//
#include <hip/hip_runtime.h>
#include <hip/hip_bf16.h>

#define NN 1500
#define GIN 32
#define GOUT 8
#define HID 128
#define CAP 192           // max nnz/row kept; mean ~60, sigma ~7.6 -> 17 sigma headroom

typedef _Float16 h2 __attribute__((ext_vector_type(2)));

__device__ __forceinline__ h2 u2h(unsigned int x) { return __builtin_bit_cast(h2, x); }
__device__ __forceinline__ unsigned int h2u(h2 x) { return __builtin_bit_cast(unsigned int, x); }

// ---------------------------------------------------------------------------
// Fused: compact combined adjacency row (geo+sem > 0) into LDS, write CSR for
// layers 2-3, and compute GAT layer 1 attention for this row in one kernel.
// One block (256 thr) per row.
// R12: pure revert to the R10 structure (147.2 us verified). R11's lane-pair
// split (8 shfl_xor + divergent epilogue per edge) cost more than the halved
// FMA tail saved -- the tail is latency-bound, not throughput-bound.
// ---------------------------------------------------------------------------
__global__ void gat_first(const float* __restrict__ geo,
                          const float* __restrict__ sem,
                          const float* __restrict__ feat,   // NN x 32
                          const float* __restrict__ W0,     // 32 x 8
                          const float* __restrict__ a0,     // 16
                          int* __restrict__ csr_idx,
                          float* __restrict__ csr_val,
                          int* __restrict__ csr_cnt,
                          float* __restrict__ enc_out) {
    const int i = blockIdx.x;
    const int t = threadIdx.x;  // 256
    __shared__ int cnt;
    __shared__ int sidx[CAP];
    __shared__ float sval[CAP];
    __shared__ float hi_s[GOUT];
    __shared__ float wsum[4][GOUT + 1];
    if (t == 0) cnt = 0;
    __syncthreads();

    const float* grow = geo + (size_t)i * NN;
    const float* srow = sem + (size_t)i * NN;
    for (int q = t; q < NN / 4; q += 256) {
        float4 g = *(const float4*)(grow + 4 * q);
        float4 s = *(const float4*)(srow + 4 * q);
        float a[4] = {g.x + s.x, g.y + s.y, g.z + s.z, g.w + s.w};
        #pragma unroll
        for (int c = 0; c < 4; ++c) {
            if (a[c] > 0.f) {
                int p = atomicAdd(&cnt, 1);
                if (p < CAP) { sidx[p] = 4 * q + c; sval[p] = a[c]; }
            }
        }
    }
    // h_i (only needed for f_src): threads 0..7
    if (t < GOUT) {
        float hv = 0.f;
        #pragma unroll 4
        for (int c = 0; c < GIN; ++c)
            hv = fmaf(feat[(size_t)i * GIN + c], W0[c * GOUT + t], hv);
        hi_s[t] = hv;
    }
    __syncthreads();

    const int c2 = cnt < CAP ? cnt : CAP;
    if (t == 0) csr_cnt[i] = c2;
    for (int p = t; p < c2; p += 256) {
        csr_idx[(size_t)i * CAP + p] = sidx[p];
        csr_val[(size_t)i * CAP + p] = sval[p];
    }
    float fsrc = 0.f;
    #pragma unroll
    for (int k = 0; k < GOUT; ++k) fsrc = fmaf(hi_s[k], a0[k], fsrc);

    // attention: one entry per thread (cnt <= 192 < 256 -> single pass)
    float den = 0.f;
    float num[GOUT] = {};
    if (t < c2) {
        int j = sidx[t];
        float a = sval[t];
        float hj[GOUT] = {};
        #pragma unroll
        for (int c4 = 0; c4 < GIN / 4; ++c4) {
            float4 e4 = *(const float4*)(feat + (size_t)j * GIN + 4 * c4);
            const float* ep = (const float*)&e4;
            #pragma unroll
            for (int c = 0; c < 4; ++c)
                #pragma unroll
                for (int k = 0; k < GOUT; ++k)
                    hj[k] = fmaf(ep[c], W0[(4 * c4 + c) * GOUT + k], hj[k]);
        }
        float fd = 0.f;
        #pragma unroll
        for (int k = 0; k < GOUT; ++k) fd = fmaf(hj[k], a0[GOUT + k], fd);
        float ev = fsrc + fd;
        ev = (ev > 0.f) ? ev : 0.2f * ev;
        ev *= a;
        float p = __expf(ev);
        den = p;
        #pragma unroll
        for (int k = 0; k < GOUT; ++k) num[k] = p * hj[k];
    }
    #pragma unroll
    for (int off = 32; off > 0; off >>= 1) {
        den += __shfl_xor(den, off, 64);
        #pragma unroll
        for (int k = 0; k < GOUT; ++k) num[k] += __shfl_xor(num[k], off, 64);
    }
    if ((t & 63) == 0) {
        wsum[t >> 6][0] = den;
        #pragma unroll
        for (int k = 0; k < GOUT; ++k) wsum[t >> 6][1 + k] = num[k];
    }
    __syncthreads();
    if (t < GOUT) {
        float L = wsum[0][0] + wsum[1][0] + wsum[2][0] + wsum[3][0];
        float v = (wsum[0][1 + t] + wsum[1][1 + t] + wsum[2][1 + t] + wsum[3][1 + t]) / L;
        enc_out[(size_t)i * GOUT + t] = (v > 0.f) ? v : (__expf(v) - 1.f);
    }
}

// ---------------------------------------------------------------------------
// GAT layers 2,3: one WAVE per row i, CSR-driven. When UV=true (layer 3),
// the wave also computes U[i,:], V[i,:] (stored as f16 for the packed-math
// MLP), A[i]=sum_k U*f2, B[i]=sum_k V*f2 (fp32 rank-1 split), and row 0's
// wave writes c = sum_k w16*f2 plus f16 copies of w16 and fc2w.
// ---------------------------------------------------------------------------
template<int IN, bool UV>
__global__ void gat_layer(const float* __restrict__ enc,
                          const float* __restrict__ W,     // IN x 8
                          const float* __restrict__ avec,  // 16
                          const int* __restrict__ csr_idx,
                          const float* __restrict__ csr_val,
                          const int* __restrict__ csr_cnt,
                          float* __restrict__ enc_out,
                          const float* __restrict__ fc1w,  // 17 x 128
                          const float* __restrict__ fc1b,  // 128
                          const float* __restrict__ fc2w,  // 128
                          _Float16* __restrict__ Uh, _Float16* __restrict__ Vh,
                          _Float16* __restrict__ wh, _Float16* __restrict__ fh,
                          float* __restrict__ Arow, float* __restrict__ Bcol,
                          float* __restrict__ cptr) {
    const int tid = threadIdx.x;            // 256 = 4 waves, 1 wave per row
    const int lane = tid & 63;
    const int i = blockIdx.x * 4 + (tid >> 6);   // 375*4 == 1500 exact

    float hv = 0.f;
    if (lane < GOUT) {
        #pragma unroll 4
        for (int c = 0; c < IN; ++c)
            hv = fmaf(enc[(size_t)i * IN + c], W[c * GOUT + lane], hv);
    }
    float hi[GOUT];
    #pragma unroll
    for (int c = 0; c < GOUT; ++c) hi[c] = __shfl(hv, c, 64);
    float fsrc = 0.f;
    #pragma unroll
    for (int c = 0; c < GOUT; ++c) fsrc = fmaf(hi[c], avec[c], fsrc);

    const int cnt = csr_cnt[i];
    float den = 0.f;
    float num[GOUT] = {};
    for (int e = lane; e < cnt; e += 64) {
        int j = csr_idx[(size_t)i * CAP + e];
        float a = csr_val[(size_t)i * CAP + e];
        float hj[GOUT] = {};
        #pragma unroll
        for (int c4 = 0; c4 < IN / 4; ++c4) {
            float4 e4 = *(const float4*)(enc + (size_t)j * IN + 4 * c4);
            const float* ep = (const float*)&e4;
            #pragma unroll
            for (int c = 0; c < 4; ++c)
                #pragma unroll
                for (int k = 0; k < GOUT; ++k)
                    hj[k] = fmaf(ep[c], W[(4 * c4 + c) * GOUT + k], hj[k]);
        }
        float fd = 0.f;
        #pragma unroll
        for (int k = 0; k < GOUT; ++k) fd = fmaf(hj[k], avec[GOUT + k], fd);
        float ev = fsrc + fd;
        ev = (ev > 0.f) ? ev : 0.2f * ev;
        ev *= a;
        float p = __expf(ev);
        den += p;
        #pragma unroll
        for (int k = 0; k < GOUT; ++k) num[k] = fmaf(p, hj[k], num[k]);
    }
    #pragma unroll
    for (int off = 32; off > 0; off >>= 1) {
        den += __shfl_xor(den, off, 64);
        #pragma unroll
        for (int k = 0; k < GOUT; ++k) num[k] += __shfl_xor(num[k], off, 64);
    }
    // elu output for this row (valid at lanes 0..7)
    float vout = 0.f;
    if (lane < GOUT) {
        float v = num[lane] / den;
        vout = (v > 0.f) ? v : (__expf(v) - 1.f);
        enc_out[(size_t)i * GOUT + lane] = vout;
    }

    if constexpr (UV) {
        float er[GOUT];
        #pragma unroll
        for (int c = 0; c < GOUT; ++c) er[c] = __shfl(vout, c, 64);
        const int kl = lane, kh = lane + 64;
        float u_lo = fc1b[kl], u_hi = fc1b[kh];
        float v_lo = 0.f, v_hi = 0.f;
        #pragma unroll
        for (int c = 0; c < GOUT; ++c) {
            u_lo = fmaf(er[c], fc1w[c * HID + kl], u_lo);
            u_hi = fmaf(er[c], fc1w[c * HID + kh], u_hi);
            v_lo = fmaf(er[c], fc1w[(GOUT + c) * HID + kl], v_lo);
            v_hi = fmaf(er[c], fc1w[(GOUT + c) * HID + kh], v_hi);
        }
        Uh[(size_t)i * HID + kl] = (_Float16)u_lo;
        Uh[(size_t)i * HID + kh] = (_Float16)u_hi;
        Vh[(size_t)i * HID + kl] = (_Float16)v_lo;
        Vh[(size_t)i * HID + kh] = (_Float16)v_hi;
        const float f_lo = fc2w[kl], f_hi = fc2w[kh];
        float ap = u_lo * f_lo + u_hi * f_hi;
        float bp = v_lo * f_lo + v_hi * f_hi;
        #pragma unroll
        for (int off = 32; off > 0; off >>= 1) {
            ap += __shfl_xor(ap, off, 64);
            bp += __shfl_xor(bp, off, 64);
        }
        if (lane == 0) { Arow[i] = ap; Bcol[i] = bp; }
        if (i == 0) {
            const float* w16g = fc1w + 2 * GOUT * HID;
            wh[kl] = (_Float16)w16g[kl];
            wh[kh] = (_Float16)w16g[kh];
            fh[kl] = (_Float16)f_lo;
            fh[kh] = (_Float16)f_hi;
            float cp = w16g[kl] * f_lo + w16g[kh] * f_hi;
            #pragma unroll
            for (int off = 32; off > 0; off >>= 1) cp += __shfl_xor(cp, off, 64);
            if (lane == 0) cptr[0] = cp;
        }
    }
}

// ---------------------------------------------------------------------------
// Pair-MLP, LDS-free lane=j, packed f16 (R10), with the scalar-load pipeline
// fixed: R10 issued one s_load_dwordx4 of U per 16 VALU (load->wait->burst
// every 32 cyc at ~100 cyc SMEM latency -> ~40% issue efficiency, the
// R8-R10 invariant). Now q-outer/r-inner: all IB row-loads batched before a
// 96-VALU burst (24 SGPRs/q; compiler can keep 2 q's in flight), one lgkm
// wait per burst instead of six.
// R12 note: R11's vn[4] one-chunk-ahead V prefetch regressed 5.6 us -- +16
// live VGPRs under __launch_bounds__(256,6)'s ~84-VGPR cap => spills. The
// ~6 waves/SIMD TLP already covers the chunk-boundary vmcnt latency.
//   per 2 k: v_pk_add_f16, v_pk_fma_f16, v_and_b32 (|.|), v_dot2_f32_f16
//   out = fc2b + 0.5*(A_i + B_j + d*c) + 0.5*sum_k |U+V+d*w16|*f2  (relu->abs)
// Grid 6 x 250 = 1500 blocks = ~5.9 waves/SIMD.
// ---------------------------------------------------------------------------
#define IB 6

__global__ __launch_bounds__(256, 6) void mlp_kernel(
        const _Float16* __restrict__ Uh, const _Float16* __restrict__ Vh,
        const _Float16* __restrict__ wh, const _Float16* __restrict__ fh,
        const float* __restrict__ Arow, const float* __restrict__ Bcol,
        const float* __restrict__ cptr,
        const float* __restrict__ dist,
        const float* __restrict__ fc2b,   // 1
        float* __restrict__ out) {
    const int tid = threadIdx.x;
    const int j = blockIdx.x * 256 + tid;        // 6*256 = 1536 covers 1500
    const int jc = j < NN ? j : NN - 1;
    const int i0 = blockIdx.y * IB;              // 250*6 = 1500 exact

    // distance strip (fp32 for epilogue + f16-pair splat for the inner fma)
    float d[IB], acc[IB];
    h2 d2[IB];
    #pragma unroll
    for (int r = 0; r < IB; ++r) {
        d[r] = dist[(size_t)(i0 + r) * NN + jc];
        acc[r] = 0.f;
        _Float16 dh = (_Float16)d[r];
        d2[r] = h2{dh, dh};
    }

    const uint4* Vrow = (const uint4*)(Vh + (size_t)jc * HID);  // 16 x uint4
    const uint4* Wt = (const uint4*)wh;
    const uint4* Ft = (const uint4*)fh;

    for (int c4 = 0; c4 < 4; ++c4) {    // 4 chunks of 32 k (8 f16 per uint4)
        uint4 vv[4], ww[4], ff[4];
        #pragma unroll
        for (int q = 0; q < 4; ++q) {
            vv[q] = Vrow[c4 * 4 + q];   // per-lane VMEM
            ww[q] = Wt[c4 * 4 + q];     // wave-uniform -> s_load
            ff[q] = Ft[c4 * 4 + q];
        }
        #pragma unroll
        for (int q = 0; q < 4; ++q) {
            // batch all IB row-loads for this q (wave-uniform -> s_load x IB)
            uint4 uu[IB];
            #pragma unroll
            for (int r = 0; r < IB; ++r)
                uu[r] = *((const uint4*)(Uh + (size_t)(i0 + r) * HID) + c4 * 4 + q);
            const unsigned int ve[4] = {vv[q].x, vv[q].y, vv[q].z, vv[q].w};
            const unsigned int we[4] = {ww[q].x, ww[q].y, ww[q].z, ww[q].w};
            const unsigned int fe[4] = {ff[q].x, ff[q].y, ff[q].z, ff[q].w};
            #pragma unroll
            for (int r = 0; r < IB; ++r) {
                const unsigned int ue[4] = {uu[r].x, uu[r].y, uu[r].z, uu[r].w};
                #pragma unroll
                for (int e = 0; e < 4; ++e) {
                    h2 t = u2h(ue[e]) + u2h(ve[e]);                       // v_pk_add_f16
                    t = __builtin_elementwise_fma(d2[r], u2h(we[e]), t);  // v_pk_fma_f16
                    t = u2h(h2u(t) & 0x7fff7fffu);                        // |.| both halves
                    acc[r] = __builtin_amdgcn_fdot2(t, u2h(fe[e]), acc[r], false);
                }
            }
        }
    }

    // epilogue: fp32 rank-1 linear half + bias, coalesced stores
    if (j < NN) {
        const float c = cptr[0];
        const float b2 = fc2b[0];
        const float Bj = Bcol[jc];
        #pragma unroll
        for (int r = 0; r < IB; ++r) {
            float lin = Arow[i0 + r] + Bj + d[r] * c;
            out[(size_t)(i0 + r) * NN + j] = fmaf(0.5f, lin + acc[r], b2);
        }
    }
}

// ---------------------------------------------------------------------------
extern "C" void kernel_launch(void* const* d_in, const int* in_sizes, int n_in,
                              void* d_out, int out_size, void* d_ws, size_t ws_size,
                              hipStream_t stream) {
    const float* geo  = (const float*)d_in[0];
    const float* sem  = (const float*)d_in[1];
    const float* feat = (const float*)d_in[2];
    // d_in[3] = region_pairs: full meshgrid -> row-major (i,j); unused
    const float* dist = (const float*)d_in[4];
    const float* W0   = (const float*)d_in[5];
    const float* W1   = (const float*)d_in[6];
    const float* W2   = (const float*)d_in[7];
    const float* a0   = (const float*)d_in[8];
    const float* a1   = (const float*)d_in[9];
    const float* a2   = (const float*)d_in[10];
    const float* fc1w = (const float*)d_in[11];
    const float* fc1b = (const float*)d_in[12];
    const float* fc2w = (const float*)d_in[13];
    const float* fc2b = (const float*)d_in[14];
    float* out = (float*)d_out;

    // workspace layout (~3.5 MB); all chunk sizes keep 16B alignment
    char* ws = (char*)d_ws;
    int*      csr_idx = (int*)ws;                     ws += sizeof(int) * NN * CAP;
    float*    csr_val = (float*)ws;                   ws += sizeof(float) * NN * CAP;
    int*      csr_cnt = (int*)ws;                     ws += sizeof(int) * NN;
    float*    encA    = (float*)ws;                   ws += sizeof(float) * NN * GOUT;
    float*    encB    = (float*)ws;                   ws += sizeof(float) * NN * GOUT;
    _Float16* Uh      = (_Float16*)ws;                ws += sizeof(_Float16) * NN * HID;
    _Float16* Vh      = (_Float16*)ws;                ws += sizeof(_Float16) * NN * HID;
    _Float16* wh      = (_Float16*)ws;                ws += sizeof(_Float16) * HID;
    _Float16* fh      = (_Float16*)ws;                ws += sizeof(_Float16) * HID;
    float*    Ar      = (float*)ws;                   ws += sizeof(float) * NN;
    float*    Bc      = (float*)ws;                   ws += sizeof(float) * NN;
    float*    cptr    = (float*)ws;

    gat_first<<<NN, 256, 0, stream>>>(geo, sem, feat, W0, a0,
                                      csr_idx, csr_val, csr_cnt, encA);
    gat_layer<GOUT, false><<<NN / 4, 256, 0, stream>>>(
        encA, W1, a1, csr_idx, csr_val, csr_cnt, encB,
        nullptr, nullptr, nullptr,
        nullptr, nullptr, nullptr, nullptr, nullptr, nullptr, nullptr);
    gat_layer<GOUT, true><<<NN / 4, 256, 0, stream>>>(
        encB, W2, a2, csr_idx, csr_val, csr_cnt, encA,
        fc1w, fc1b, fc2w, Uh, Vh, wh, fh, Ar, Bc, cptr);

    dim3 mg((NN + 255) / 256, (NN + IB - 1) / IB);   // 6 x 250
    mlp_kernel<<<mg, 256, 0, stream>>>(Uh, Vh, wh, fh, Ar, Bc, cptr,
                                       dist, fc2b, out);
}